// Round 7
// baseline (384.485 us; speedup 1.0000x reference)
//
#include <hip/hip_runtime.h>

#define BSZ   64
#define TLEN  2048
#define NSTEP 2047
#define CIN   8
#define MD    16
#define STR   20      // LDS row stride in floats: 80B, 16B-aligned, 2-way-max banks
#define NCH   128     // chunks per batch
#define CHL   16      // steps per chunk

__global__ __launch_bounds__(256)
void devnet_expm_chunk(const float* __restrict__ X, const float* __restrict__ A,
                       float* __restrict__ G)
{
    __shared__ __align__(16) float Xs[4][MD][STR];
    __shared__ __align__(16) float Rs[4][MD][STR];
    __shared__ __align__(16) float Ps[4][MD][STR];

    const int tid  = threadIdx.x;
    const int wid  = tid >> 6;
    const int lane = tid & 63;
    const int i    = lane >> 2;    // output row 0..15
    const int j4   = lane & 3;     // output col quartet
    const int gw   = blockIdx.x * 4 + wid;
    const int b    = gw >> 7;      // 128 chunks per batch
    const int c    = gw & (NCH - 1);

    float (*xs)[STR] = Xs[wid];
    float (*rs)[STR] = Rs[wid];
    float (*ps)[STR] = Ps[wid];

    // A_skew fragment this thread needs: rows i, cols 4*j4+q
    float ask[4][CIN];
#pragma unroll
    for (int q = 0; q < 4; ++q) {
        const int jj = 4 * j4 + q;
#pragma unroll
        for (int cc = 0; cc < CIN; ++cc)
            ask[q][cc] = A[(i * MD + jj) * CIN + cc] - A[(jj * MD + i) * CIN + cc];
    }

    // P = I
    {
        float4 v;
        v.x = (i == 4 * j4 + 0) ? 1.f : 0.f;
        v.y = (i == 4 * j4 + 1) ? 1.f : 0.f;
        v.z = (i == 4 * j4 + 2) ? 1.f : 0.f;
        v.w = (i == 4 * j4 + 3) ? 1.f : 0.f;
        *reinterpret_cast<float4*>(&ps[i][4 * j4]) = v;
    }

    const int t0 = c * CHL;
    const int t1 = (t0 + CHL < NSTEP) ? (t0 + CHL) : NSTEP;

    for (int t = t0; t < t1; ++t) {
        // dX[t] = X[b,t+1,:] - X[b,t,:]
        const float* xp = X + ((size_t)b * TLEN + t) * CIN;
        const float4 x0 = *reinterpret_cast<const float4*>(xp + 0);
        const float4 x1 = *reinterpret_cast<const float4*>(xp + 4);
        const float4 y0 = *reinterpret_cast<const float4*>(xp + 8);
        const float4 y1 = *reinterpret_cast<const float4*>(xp + 12);
        float dx[CIN];
        dx[0] = y0.x - x0.x; dx[1] = y0.y - x0.y; dx[2] = y0.z - x0.z; dx[3] = y0.w - x0.w;
        dx[4] = y1.x - x1.x; dx[5] = y1.y - x1.y; dx[6] = y1.z - x1.z; dx[7] = y1.w - x1.w;

        // S strip (row i, cols 4*j4..+3)
        float sv[4];
#pragma unroll
        for (int q = 0; q < 4; ++q) {
            float acc = 0.f;
#pragma unroll
            for (int cc = 0; cc < CIN; ++cc) acc = fmaf(dx[cc], ask[q][cc], acc);
            sv[q] = acc;
        }

        // inf-norm = max_i sum_j |S[i][j]|  (4 lanes per row, then max over 16 rows)
        float a = fabsf(sv[0]) + fabsf(sv[1]) + fabsf(sv[2]) + fabsf(sv[3]);
        a += __shfl_xor(a, 1, 64);
        a += __shfl_xor(a, 2, 64);
        a = fmaxf(a, __shfl_xor(a, 4, 64));
        a = fmaxf(a, __shfl_xor(a, 8, 64));
        a = fmaxf(a, __shfl_xor(a, 16, 64));
        a = fmaxf(a, __shfl_xor(a, 32, 64));

        int sc = 0;
        float scale = 1.f;
        while (a > 0.5f && sc < 40) { a *= 0.5f; scale *= 0.5f; ++sc; }

        // scaled S into LDS; cache full row i in registers
        float4 xv;
        xv.x = sv[0] * scale; xv.y = sv[1] * scale;
        xv.z = sv[2] * scale; xv.w = sv[3] * scale;
        *reinterpret_cast<float4*>(&xs[i][4 * j4]) = xv;

        // R = I + X/8 (degree-8 Taylor, Horner)
        float4 rv;
        rv.x = ((i == 4 * j4 + 0) ? 1.f : 0.f) + xv.x * 0.125f;
        rv.y = ((i == 4 * j4 + 1) ? 1.f : 0.f) + xv.y * 0.125f;
        rv.z = ((i == 4 * j4 + 2) ? 1.f : 0.f) + xv.z * 0.125f;
        rv.w = ((i == 4 * j4 + 3) ? 1.f : 0.f) + xv.w * 0.125f;
        *reinterpret_cast<float4*>(&rs[i][4 * j4]) = rv;

        float xrow[MD];
#pragma unroll
        for (int r4 = 0; r4 < 4; ++r4) {
            float4 tv = *reinterpret_cast<const float4*>(&xs[i][4 * r4]);
            xrow[4 * r4 + 0] = tv.x; xrow[4 * r4 + 1] = tv.y;
            xrow[4 * r4 + 2] = tv.z; xrow[4 * r4 + 3] = tv.w;
        }

        // Horner k = 7..1 : R <- I + (X/k) @ R
#pragma unroll
        for (int k = 7; k >= 1; --k) {
            float ax = 0.f, ay = 0.f, az = 0.f, aw = 0.f;
#pragma unroll
            for (int p = 0; p < MD; ++p) {
                float4 col = *reinterpret_cast<const float4*>(&rs[p][4 * j4]);
                ax = fmaf(xrow[p], col.x, ax);
                ay = fmaf(xrow[p], col.y, ay);
                az = fmaf(xrow[p], col.z, az);
                aw = fmaf(xrow[p], col.w, aw);
            }
            const float inv = 1.f / (float)k;
            float4 nv;
            nv.x = ((i == 4 * j4 + 0) ? 1.f : 0.f) + ax * inv;
            nv.y = ((i == 4 * j4 + 1) ? 1.f : 0.f) + ay * inv;
            nv.z = ((i == 4 * j4 + 2) ? 1.f : 0.f) + az * inv;
            nv.w = ((i == 4 * j4 + 3) ? 1.f : 0.f) + aw * inv;
            *reinterpret_cast<float4*>(&rs[i][4 * j4]) = nv;
        }

        // squarings: R <- R @ R
        for (int q = 0; q < sc; ++q) {
            float rrow[MD];
#pragma unroll
            for (int r4 = 0; r4 < 4; ++r4) {
                float4 tv = *reinterpret_cast<const float4*>(&rs[i][4 * r4]);
                rrow[4 * r4 + 0] = tv.x; rrow[4 * r4 + 1] = tv.y;
                rrow[4 * r4 + 2] = tv.z; rrow[4 * r4 + 3] = tv.w;
            }
            float ax = 0.f, ay = 0.f, az = 0.f, aw = 0.f;
#pragma unroll
            for (int p = 0; p < MD; ++p) {
                float4 col = *reinterpret_cast<const float4*>(&rs[p][4 * j4]);
                ax = fmaf(rrow[p], col.x, ax);
                ay = fmaf(rrow[p], col.y, ay);
                az = fmaf(rrow[p], col.z, az);
                aw = fmaf(rrow[p], col.w, aw);
            }
            float4 nv; nv.x = ax; nv.y = ay; nv.z = az; nv.w = aw;
            *reinterpret_cast<float4*>(&rs[i][4 * j4]) = nv;
        }

        // chain: P <- R @ P  (later time on the left)
        {
            float rrow[MD];
#pragma unroll
            for (int r4 = 0; r4 < 4; ++r4) {
                float4 tv = *reinterpret_cast<const float4*>(&rs[i][4 * r4]);
                rrow[4 * r4 + 0] = tv.x; rrow[4 * r4 + 1] = tv.y;
                rrow[4 * r4 + 2] = tv.z; rrow[4 * r4 + 3] = tv.w;
            }
            float ax = 0.f, ay = 0.f, az = 0.f, aw = 0.f;
#pragma unroll
            for (int p = 0; p < MD; ++p) {
                float4 col = *reinterpret_cast<const float4*>(&ps[p][4 * j4]);
                ax = fmaf(rrow[p], col.x, ax);
                ay = fmaf(rrow[p], col.y, ay);
                az = fmaf(rrow[p], col.z, az);
                aw = fmaf(rrow[p], col.w, aw);
            }
            float4 nv; nv.x = ax; nv.y = ay; nv.z = az; nv.w = aw;
            *reinterpret_cast<float4*>(&ps[i][4 * j4]) = nv;
        }
    }

    // emit chunk product
    const float4 res = *reinterpret_cast<const float4*>(&ps[i][4 * j4]);
    float* gp = G + ((size_t)b * NCH + c) * 256 + i * MD + 4 * j4;
    *reinterpret_cast<float4*>(gp) = res;
}

__global__ __launch_bounds__(256)
void devnet_reduce(const float* __restrict__ G, const float* __restrict__ W,
                   const float* __restrict__ bias, float* __restrict__ out)
{
    __shared__ __align__(16) float Ps[4][MD][STR];
    __shared__ float red[10][4];

    const int tid  = threadIdx.x;
    const int wid  = tid >> 6;
    const int lane = tid & 63;
    const int i    = lane >> 2;
    const int j4   = lane & 3;
    const int b    = blockIdx.x;

    // wave w: product of chunk matrices [32w .. 32w+31], sequential, later on left
    {
        const float* g0 = G + ((size_t)b * NCH + wid * 32) * 256;
        float4 v = *reinterpret_cast<const float4*>(&g0[i * MD + 4 * j4]);
        *reinterpret_cast<float4*>(&Ps[wid][i][4 * j4]) = v;
    }
    for (int cc = 1; cc < 32; ++cc) {
        const float* gc = G + ((size_t)b * NCH + wid * 32 + cc) * 256;
        float lrow[MD];
#pragma unroll
        for (int r4 = 0; r4 < 4; ++r4) {
            float4 tv = *reinterpret_cast<const float4*>(&gc[i * MD + 4 * r4]);
            lrow[4 * r4 + 0] = tv.x; lrow[4 * r4 + 1] = tv.y;
            lrow[4 * r4 + 2] = tv.z; lrow[4 * r4 + 3] = tv.w;
        }
        float ax = 0.f, ay = 0.f, az = 0.f, aw = 0.f;
#pragma unroll
        for (int p = 0; p < MD; ++p) {
            float4 col = *reinterpret_cast<const float4*>(&Ps[wid][p][4 * j4]);
            ax = fmaf(lrow[p], col.x, ax);
            ay = fmaf(lrow[p], col.y, ay);
            az = fmaf(lrow[p], col.z, az);
            aw = fmaf(lrow[p], col.w, aw);
        }
        float4 nv; nv.x = ax; nv.y = ay; nv.z = az; nv.w = aw;
        *reinterpret_cast<float4*>(&Ps[wid][i][4 * j4]) = nv;
    }

    __syncthreads();

    // combine: Z = Q3 @ Q2 @ Q1 @ Q0, done by wave 0 into Ps[0]
    if (wid == 0) {
        for (int w2 = 1; w2 < 4; ++w2) {
            float rrow[MD];
#pragma unroll
            for (int r4 = 0; r4 < 4; ++r4) {
                float4 tv = *reinterpret_cast<const float4*>(&Ps[w2][i][4 * r4]);
                rrow[4 * r4 + 0] = tv.x; rrow[4 * r4 + 1] = tv.y;
                rrow[4 * r4 + 2] = tv.z; rrow[4 * r4 + 3] = tv.w;
            }
            float ax = 0.f, ay = 0.f, az = 0.f, aw = 0.f;
#pragma unroll
            for (int p = 0; p < MD; ++p) {
                float4 col = *reinterpret_cast<const float4*>(&Ps[0][p][4 * j4]);
                ax = fmaf(rrow[p], col.x, ax);
                ay = fmaf(rrow[p], col.y, ay);
                az = fmaf(rrow[p], col.z, az);
                aw = fmaf(rrow[p], col.w, aw);
            }
            float4 nv; nv.x = ax; nv.y = ay; nv.z = az; nv.w = aw;
            *reinterpret_cast<float4*>(&Ps[0][i][4 * j4]) = nv;
        }
    }
    __syncthreads();

    // out[b,o] = sum_k Z_flat[k] * W[o,k] + bias[o]
    const int zi = tid >> 4, zj = tid & 15;
    const float z = Ps[0][zi][zj];
    for (int o = 0; o < 10; ++o) {
        float v = z * W[o * 256 + tid];
#pragma unroll
        for (int off = 32; off >= 1; off >>= 1) v += __shfl_down(v, off, 64);
        if (lane == 0) red[o][wid] = v;
    }
    __syncthreads();
    if (tid < 10)
        out[b * 10 + tid] = red[tid][0] + red[tid][1] + red[tid][2] + red[tid][3] + bias[tid];
}

extern "C" void kernel_launch(void* const* d_in, const int* in_sizes, int n_in,
                              void* d_out, int out_size, void* d_ws, size_t ws_size,
                              hipStream_t stream)
{
    const float* X    = (const float*)d_in[0];
    const float* A    = (const float*)d_in[1];
    const float* W    = (const float*)d_in[2];
    const float* bias = (const float*)d_in[3];
    float* out = (float*)d_out;
    float* G   = (float*)d_ws;   // 64*128*256 floats = 8 MB of scratch

    devnet_expm_chunk<<<BSZ * NCH / 4, 256, 0, stream>>>(X, A, G);
    devnet_reduce<<<BSZ, 256, 0, stream>>>(G, W, bias, out);
}

// Round 8
// 205.936 us; speedup vs baseline: 1.8670x; 1.8670x over previous
//
#include <hip/hip_runtime.h>

#define BSZ   64
#define TLEN  2048
#define NSTEP 2047
#define CIN   8
#define NCH   128     // chunks per batch
#define CHL   16      // steps per chunk
#define TSTR  20      // LDS transpose-buffer row stride (floats)

typedef __attribute__((ext_vector_type(4))) float    fx4;
typedef __attribute__((ext_vector_type(4))) _Float16 hx4;

// f32 -> f16 hi/lo split: hi+lo represents v to ~2^-23 relative
__device__ __forceinline__ void splitf(const fx4 v, hx4& hi, hx4& lo) {
    _Float16 h0 = (_Float16)v[0], h1 = (_Float16)v[1];
    _Float16 h2 = (_Float16)v[2], h3 = (_Float16)v[3];
    hi[0] = h0; hi[1] = h1; hi[2] = h2; hi[3] = h3;
    lo[0] = (_Float16)(v[0] - (float)h0);
    lo[1] = (_Float16)(v[1] - (float)h1);
    lo[2] = (_Float16)(v[2] - (float)h2);
    lo[3] = (_Float16)(v[3] - (float)h3);
}

// D = A*B with 3-term split (error ~2^-23): hh + h*l + l*h
__device__ __forceinline__ fx4 mm3(hx4 ah, hx4 al, hx4 bh, hx4 bl) {
    fx4 acc = {0.f, 0.f, 0.f, 0.f};
    acc = __builtin_amdgcn_mfma_f32_16x16x16f16(ah, bh, acc, 0, 0, 0);
    acc = __builtin_amdgcn_mfma_f32_16x16x16f16(ah, bl, acc, 0, 0, 0);
    acc = __builtin_amdgcn_mfma_f32_16x16x16f16(al, bh, acc, 0, 0, 0);
    return acc;
}

// Wave-local LDS transpose: v is the B/D-frag of M (lane holds M[4m+r][c]);
// returns the A-frag of M (lane holds M[c][4m+r]). In-order DS pipe + compiler
// lgkmcnt ordering make this safe without barriers (single-wave buffer).
__device__ __forceinline__ fx4 ldsT(float (*ts)[TSTR], int m, int c, fx4 v) {
    ts[4 * m + 0][c] = v[0];
    ts[4 * m + 1][c] = v[1];
    ts[4 * m + 2][c] = v[2];
    ts[4 * m + 3][c] = v[3];
    return *(const fx4*)&ts[c][4 * m];   // 16B-aligned: (20c+4m)*4
}

__global__ __launch_bounds__(256)
void devnet_expm_chunk(const float* __restrict__ X, const float* __restrict__ A,
                       float* __restrict__ G)
{
    __shared__ __align__(16) float Ts[4][16][TSTR];

    const int tid  = threadIdx.x;
    const int wid  = tid >> 6;
    const int lane = tid & 63;
    const int m    = lane >> 4;   // row-quad (B/D) / k-quad (A)
    const int c    = lane & 15;   // column (B/D) / row (A)
    const int gw   = blockIdx.x * 4 + wid;
    const int b    = gw >> 7;
    const int ch   = gw & (NCH - 1);
    float (*ts)[TSTR] = Ts[wid];

    // A_skew slices for this lane's B-frag: rows 4m+r, col c, all 8 channels
    float ask[4][CIN];
#pragma unroll
    for (int r = 0; r < 4; ++r) {
        const int i = 4 * m + r;
#pragma unroll
        for (int cc = 0; cc < CIN; ++cc)
            ask[r][cc] = A[(i * 16 + c) * CIN + cc] - A[(c * 16 + i) * CIN + cc];
    }

    // identity in B-frag layout
    fx4 idv;
#pragma unroll
    for (int r = 0; r < 4; ++r) idv[r] = (4 * m + r == c) ? 1.f : 0.f;

    fx4 P = idv;   // running chunk product (B/D layout)

    const int t0 = ch * CHL;
    const int t1 = (t0 + CHL < NSTEP) ? (t0 + CHL) : NSTEP;

    for (int t = t0; t < t1; ++t) {
        // dX[t] = X[b,t+1,:] - X[b,t,:]
        const float* xp = X + ((size_t)b * TLEN + t) * CIN;
        const float4 x0 = *reinterpret_cast<const float4*>(xp + 0);
        const float4 x1 = *reinterpret_cast<const float4*>(xp + 4);
        const float4 y0 = *reinterpret_cast<const float4*>(xp + 8);
        const float4 y1 = *reinterpret_cast<const float4*>(xp + 12);
        float dx[CIN];
        dx[0] = y0.x - x0.x; dx[1] = y0.y - x0.y; dx[2] = y0.z - x0.z; dx[3] = y0.w - x0.w;
        dx[4] = y1.x - x1.x; dx[5] = y1.y - x1.y; dx[6] = y1.z - x1.z; dx[7] = y1.w - x1.w;

        // S B-frag: sv[r] = S[4m+r][c]
        fx4 sv;
#pragma unroll
        for (int r = 0; r < 4; ++r) {
            float acc = 0.f;
#pragma unroll
            for (int cc = 0; cc < CIN; ++cc) acc = fmaf(dx[cc], ask[r][cc], acc);
            sv[r] = acc;
        }

        // norm = max column abs-sum (== inf-norm for skew S): sum rows (xor 16,32),
        // then max over columns (xor 1,2,4,8)
        float a = fabsf(sv[0]) + fabsf(sv[1]) + fabsf(sv[2]) + fabsf(sv[3]);
        a += __shfl_xor(a, 16, 64);
        a += __shfl_xor(a, 32, 64);
        a = fmaxf(a, __shfl_xor(a, 1, 64));
        a = fmaxf(a, __shfl_xor(a, 2, 64));
        a = fmaxf(a, __shfl_xor(a, 4, 64));
        a = fmaxf(a, __shfl_xor(a, 8, 64));

        int sc = 0;
        float scale = 1.f;
        while (a > 0.5f && sc < 40) { a *= 0.5f; scale *= 0.5f; ++sc; }

        // scaled X: B-frag xv; A-frag = -xv (skew symmetry => transpose is free)
        fx4 xv = sv * scale;
        fx4 nxv = -xv;
        hx4 Xah, Xal;
        splitf(nxv, Xah, Xal);

        // degree-8 Taylor, Horner: R <- I + (X/k) @ R, k = 8..1
        fx4 R = idv + xv * 0.125f;
#pragma unroll
        for (int k = 7; k >= 1; --k) {
            hx4 Rh, Rl;
            splitf(R, Rh, Rl);
            fx4 acc = mm3(Xah, Xal, Rh, Rl);      // X @ R
            R = idv + acc * (1.f / (float)k);
        }

        // squarings: R <- R @ R  (A-frag via wave-local LDS transpose)
        for (int q = 0; q < sc; ++q) {
            fx4 Ra = ldsT(ts, m, c, R);
            hx4 Ah, Al, Bh, Bl;
            splitf(Ra, Ah, Al);
            splitf(R, Bh, Bl);
            R = mm3(Ah, Al, Bh, Bl);
        }

        // chain: P <- R @ P (later factor on the left)
        {
            fx4 Ra = ldsT(ts, m, c, R);
            hx4 Ah, Al, Ph, Pl;
            splitf(Ra, Ah, Al);
            splitf(P, Ph, Pl);
            P = mm3(Ah, Al, Ph, Pl);
        }
    }

    // store raw B-frag, lane-linear (coalesced); reduce kernel consumes fragments
    *reinterpret_cast<fx4*>(G + ((size_t)b * NCH + ch) * 256 + lane * 4) = P;
}

__global__ __launch_bounds__(256)
void devnet_reduce(const float* __restrict__ G, const float* __restrict__ W,
                   const float* __restrict__ bias, float* __restrict__ out)
{
    __shared__ __align__(16) float Ts[4][16][TSTR];
    __shared__ __align__(16) float Fs[4][256];
    __shared__ float Zf[256];
    __shared__ float red[10][4];

    const int tid  = threadIdx.x;
    const int wid  = tid >> 6;
    const int lane = tid & 63;
    const int m    = lane >> 4;
    const int c    = lane & 15;
    const int b    = blockIdx.x;
    float (*ts)[TSTR] = Ts[wid];

    const float* gb = G + (size_t)b * NCH * 256;

    // wave w: Q_w = G[32w+31] @ ... @ G[32w]  (fragments chained via MFMA)
    fx4 Acc = *reinterpret_cast<const fx4*>(gb + (size_t)(wid * 32) * 256 + lane * 4);
    for (int cc = 1; cc < 32; ++cc) {
        fx4 Q = *reinterpret_cast<const fx4*>(gb + (size_t)(wid * 32 + cc) * 256 + lane * 4);
        fx4 Qa = ldsT(ts, m, c, Q);
        hx4 Ah, Al, Bh, Bl;
        splitf(Qa, Ah, Al);
        splitf(Acc, Bh, Bl);
        Acc = mm3(Ah, Al, Bh, Bl);    // Acc <- Q @ Acc
    }
    *reinterpret_cast<fx4*>(&Fs[wid][lane * 4]) = Acc;
    __syncthreads();

    // wave 0: Z = Q3 @ Q2 @ Q1 @ Q0
    if (wid == 0) {
        for (int w2 = 1; w2 < 4; ++w2) {
            fx4 Q = *reinterpret_cast<const fx4*>(&Fs[w2][lane * 4]);
            fx4 Qa = ldsT(ts, m, c, Q);
            hx4 Ah, Al, Bh, Bl;
            splitf(Qa, Ah, Al);
            splitf(Acc, Bh, Bl);
            Acc = mm3(Ah, Al, Bh, Bl);
        }
        // scatter Z (B-frag rows 4m+r, col c) to row-major flat
#pragma unroll
        for (int r = 0; r < 4; ++r) Zf[(4 * m + r) * 16 + c] = Acc[r];
    }
    __syncthreads();

    // out[b,o] = sum_k Z_flat[k] * W[o,k] + bias[o]
    const float z = Zf[tid];
    for (int o = 0; o < 10; ++o) {
        float v = z * W[o * 256 + tid];
#pragma unroll
        for (int off = 32; off >= 1; off >>= 1) v += __shfl_down(v, off, 64);
        if (lane == 0) red[o][wid] = v;
    }
    __syncthreads();
    if (tid < 10)
        out[b * 10 + tid] = red[tid][0] + red[tid][1] + red[tid][2] + red[tid][3] + bias[tid];
}

extern "C" void kernel_launch(void* const* d_in, const int* in_sizes, int n_in,
                              void* d_out, int out_size, void* d_ws, size_t ws_size,
                              hipStream_t stream)
{
    const float* X    = (const float*)d_in[0];
    const float* A    = (const float*)d_in[1];
    const float* W    = (const float*)d_in[2];
    const float* bias = (const float*)d_in[3];
    float* out = (float*)d_out;
    float* G   = (float*)d_ws;   // 64*128*256 floats = 8 MB scratch

    devnet_expm_chunk<<<BSZ * NCH / 4, 256, 0, stream>>>(X, A, G);
    devnet_reduce<<<BSZ, 256, 0, stream>>>(G, W, bias, out);
}

// Round 9
// 194.524 us; speedup vs baseline: 1.9765x; 1.0587x over previous
//
#include <hip/hip_runtime.h>

#define BSZ   64
#define TLEN  2048
#define NSTEP 2047
#define CIN   8
#define NCH   128     // chunks per batch
#define CHL   16      // steps per chunk
#define TSTR  20      // LDS transpose-buffer row stride (4B words)

typedef __attribute__((ext_vector_type(4))) float        fx4;
typedef __attribute__((ext_vector_type(4))) _Float16     hx4;
typedef __attribute__((ext_vector_type(2))) unsigned int ux2;
typedef __attribute__((ext_vector_type(4))) unsigned int ux4;

// f32 -> f16 hi/lo split (rne): hi+lo represents v to ~2^-23 relative
__device__ __forceinline__ void splitf(const fx4 v, hx4& hi, hx4& lo) {
    _Float16 h0 = (_Float16)v[0], h1 = (_Float16)v[1];
    _Float16 h2 = (_Float16)v[2], h3 = (_Float16)v[3];
    hi[0] = h0; hi[1] = h1; hi[2] = h2; hi[3] = h3;
    lo[0] = (_Float16)(v[0] - (float)h0);
    lo[1] = (_Float16)(v[1] - (float)h1);
    lo[2] = (_Float16)(v[2] - (float)h2);
    lo[3] = (_Float16)(v[3] - (float)h3);
}

// D = A*B with 3-term split (drops ll term, ~2^-22): hh + h*l + l*h
__device__ __forceinline__ fx4 mm3(hx4 ah, hx4 al, hx4 bh, hx4 bl) {
    fx4 acc = {0.f, 0.f, 0.f, 0.f};
    acc = __builtin_amdgcn_mfma_f32_16x16x16f16(ah, bh, acc, 0, 0, 0);
    acc = __builtin_amdgcn_mfma_f32_16x16x16f16(ah, bl, acc, 0, 0, 0);
    acc = __builtin_amdgcn_mfma_f32_16x16x16f16(al, bh, acc, 0, 0, 0);
    return acc;
}

// f32 wave-local LDS transpose: B-frag of M -> B-frag of M^T (= A-frag of M).
// Safe without barriers: single-wave buffer, in-order DS pipe + compiler lgkmcnt.
__device__ __forceinline__ fx4 ldsT(float* ts, int m, int c, fx4 v) {
    ts[(4 * m + 0) * TSTR + c] = v[0];
    ts[(4 * m + 1) * TSTR + c] = v[1];
    ts[(4 * m + 2) * TSTR + c] = v[2];
    ts[(4 * m + 3) * TSTR + c] = v[3];
    return *(const fx4*)&ts[c * TSTR + 4 * m];   // (20c+4m)*4B: 16B-aligned
}

// Transpose the f16 hi/lo halves of a split through LDS (packed (hi,lo) u32).
// transpose(split(M)) == split(M^T) exactly (split is elementwise).
__device__ __forceinline__ void ldsT_h(unsigned* tsu, int m, int c,
                                       hx4 Bh, hx4 Bl, hx4& Ah, hx4& Al) {
    ux2 bh = __builtin_bit_cast(ux2, Bh);
    ux2 bl = __builtin_bit_cast(ux2, Bl);
    unsigned w0 = (bh[0] & 0xFFFFu) | (bl[0] << 16);
    unsigned w1 = (bh[0] >> 16)     | (bl[0] & 0xFFFF0000u);
    unsigned w2 = (bh[1] & 0xFFFFu) | (bl[1] << 16);
    unsigned w3 = (bh[1] >> 16)     | (bl[1] & 0xFFFF0000u);
    tsu[(4 * m + 0) * TSTR + c] = w0;   // banks: (16m+20r+c)%32 -> 2-way max
    tsu[(4 * m + 1) * TSTR + c] = w1;
    tsu[(4 * m + 2) * TSTR + c] = w2;
    tsu[(4 * m + 3) * TSTR + c] = w3;
    ux4 rd = *(const ux4*)&tsu[c * TSTR + 4 * m];
    ux2 ah, al;
    ah[0] = (rd[0] & 0xFFFFu) | (rd[1] << 16);
    al[0] = (rd[0] >> 16)     | (rd[1] & 0xFFFF0000u);
    ah[1] = (rd[2] & 0xFFFFu) | (rd[3] << 16);
    al[1] = (rd[2] >> 16)     | (rd[3] & 0xFFFF0000u);
    Ah = __builtin_bit_cast(hx4, ah);
    Al = __builtin_bit_cast(hx4, al);
}

__global__ __launch_bounds__(256)
void devnet_expm_chunk(const float* __restrict__ X, const float* __restrict__ A,
                       float* __restrict__ G)
{
    __shared__ __align__(16) unsigned Ts[4][16 * TSTR];

    const int tid  = threadIdx.x;
    const int wid  = tid >> 6;
    const int lane = tid & 63;
    const int m    = lane >> 4;   // row-quad (B/D) / k-quad (A)
    const int c    = lane & 15;   // column (B/D) / row (A)
    const int gw   = blockIdx.x * 4 + wid;
    const int b    = gw >> 7;
    const int ch   = gw & (NCH - 1);
    unsigned* tsu = Ts[wid];
    float*    tsf = (float*)Ts[wid];

    // A_skew slices for this lane's B-frag: rows 4m+r, col c, all 8 channels
    float ask[4][CIN];
#pragma unroll
    for (int r = 0; r < 4; ++r) {
        const int i = 4 * m + r;
#pragma unroll
        for (int cc = 0; cc < CIN; ++cc)
            ask[r][cc] = A[(i * 16 + c) * CIN + cc] - A[(c * 16 + i) * CIN + cc];
    }

    // identity in B-frag layout
    fx4 idv;
#pragma unroll
    for (int r = 0; r < 4; ++r) idv[r] = (4 * m + r == c) ? 1.f : 0.f;

    fx4 P = idv;   // running chunk product (B/D layout)

    const int t0 = ch * CHL;
    const int t1 = (t0 + CHL < NSTEP) ? (t0 + CHL) : NSTEP;

    for (int t = t0; t < t1; ++t) {
        // dX[t] = X[b,t+1,:] - X[b,t,:]  (wave-uniform scalar loads)
        const float* xp = X + ((size_t)b * TLEN + t) * CIN;
        const float4 x0 = *reinterpret_cast<const float4*>(xp + 0);
        const float4 x1 = *reinterpret_cast<const float4*>(xp + 4);
        const float4 y0 = *reinterpret_cast<const float4*>(xp + 8);
        const float4 y1 = *reinterpret_cast<const float4*>(xp + 12);
        float dx[CIN];
        dx[0] = y0.x - x0.x; dx[1] = y0.y - x0.y; dx[2] = y0.z - x0.z; dx[3] = y0.w - x0.w;
        dx[4] = y1.x - x1.x; dx[5] = y1.y - x1.y; dx[6] = y1.z - x1.z; dx[7] = y1.w - x1.w;

        // S B-frag: sv[r] = S[4m+r][c]
        fx4 sv;
#pragma unroll
        for (int r = 0; r < 4; ++r) {
            float acc = 0.f;
#pragma unroll
            for (int cc = 0; cc < CIN; ++cc) acc = fmaf(dx[cc], ask[r][cc], acc);
            sv[r] = acc;
        }

        // inf-norm (skew: max col abs-sum == max row abs-sum)
        float a = fabsf(sv[0]) + fabsf(sv[1]) + fabsf(sv[2]) + fabsf(sv[3]);
        a += __shfl_xor(a, 16, 64);
        a += __shfl_xor(a, 32, 64);
        a = fmaxf(a, __shfl_xor(a, 1, 64));
        a = fmaxf(a, __shfl_xor(a, 2, 64));
        a = fmaxf(a, __shfl_xor(a, 4, 64));
        a = fmaxf(a, __shfl_xor(a, 8, 64));

        // exact scaling: a = mant*2^e, mant in [0.5,1); sc = max(0, e+2)
        // guarantees a*2^-sc < 0.25  (deg-5 Taylor error then <= 3.5e-7)
        int e;
        (void)frexpf(a, &e);
        int sc = e + 2;
        if (sc < 0) sc = 0;
        const float scale = ldexpf(1.0f, -sc);   // exact power of two

        // scaled X: B-frag xv; A-frag = -xv (skew symmetry: transpose is free)
        fx4 xv = sv * scale;
        fx4 nxv = -xv;
        hx4 Xah, Xal;
        splitf(nxv, Xah, Xal);

        // degree-5 Taylor, Horner: R = I + X/5; then R <- I + (X@R)/k, k=4..1
        fx4 R = idv + xv * 0.2f;
#pragma unroll
        for (int k = 4; k >= 1; --k) {
            hx4 Rh, Rl;
            splitf(R, Rh, Rl);
            fx4 acc = mm3(Xah, Xal, Rh, Rl);      // X @ R
            R = idv + acc * (1.f / (float)k);
        }

        // squarings: R <- R @ R  (split once; transpose the halves through LDS)
        for (int q = 0; q < sc; ++q) {
            hx4 Bh, Bl, Ah, Al;
            splitf(R, Bh, Bl);
            ldsT_h(tsu, m, c, Bh, Bl, Ah, Al);
            R = mm3(Ah, Al, Bh, Bl);
        }

        // chain: P <- R @ P (later factor on the left)
        {
            fx4 Ra = ldsT(tsf, m, c, R);
            hx4 Ah, Al, Ph, Pl;
            splitf(Ra, Ah, Al);
            splitf(P, Ph, Pl);
            P = mm3(Ah, Al, Ph, Pl);
        }
    }

    // store raw B-frag, lane-linear (coalesced)
    *reinterpret_cast<fx4*>(G + ((size_t)b * NCH + ch) * 256 + lane * 4) = P;
}

// stage 1: 256 blocks x 1 wave; block (b,w) folds chunks [32w..32w+31] of batch b
// and writes the product in place over chunk slot 32w.
__global__ __launch_bounds__(64)
void devnet_reduce1(float* __restrict__ G)
{
    __shared__ __align__(16) float Ts[16 * TSTR];

    const int lane = threadIdx.x;
    const int m    = lane >> 4;
    const int c    = lane & 15;
    const int b    = blockIdx.x >> 2;
    const int w    = blockIdx.x & 3;

    float* base = G + ((size_t)b * NCH + w * 32) * 256;

    fx4 Acc = *reinterpret_cast<const fx4*>(base + lane * 4);
    for (int cc = 1; cc < 32; ++cc) {
        fx4 Q  = *reinterpret_cast<const fx4*>(base + (size_t)cc * 256 + lane * 4);
        fx4 Qa = ldsT(Ts, m, c, Q);
        hx4 Ah, Al, Bh, Bl;
        splitf(Qa, Ah, Al);
        splitf(Acc, Bh, Bl);
        Acc = mm3(Ah, Al, Bh, Bl);    // Acc <- Q @ Acc
    }
    *reinterpret_cast<fx4*>(base + lane * 4) = Acc;   // exclusive region: no race
}

// stage 2: 64 blocks x 1 wave; Z = Q3 @ Q2 @ Q1 @ Q0, then out = Z_flat @ W^T + b
__global__ __launch_bounds__(64)
void devnet_reduce2(const float* __restrict__ G, const float* __restrict__ W,
                    const float* __restrict__ bias, float* __restrict__ out)
{
    __shared__ __align__(16) float Ts[16 * TSTR];
    __shared__ float Zf[256];

    const int lane = threadIdx.x;
    const int m    = lane >> 4;
    const int c    = lane & 15;
    const int b    = blockIdx.x;

    const float* gb = G + (size_t)b * NCH * 256;

    fx4 Acc = *reinterpret_cast<const fx4*>(gb + lane * 4);
    for (int w = 1; w < 4; ++w) {
        fx4 Q  = *reinterpret_cast<const fx4*>(gb + (size_t)(w * 32) * 256 + lane * 4);
        fx4 Qa = ldsT(Ts, m, c, Q);
        hx4 Ah, Al, Bh, Bl;
        splitf(Qa, Ah, Al);
        splitf(Acc, Bh, Bl);
        Acc = mm3(Ah, Al, Bh, Bl);
    }
    // scatter Z (B-frag rows 4m+r, col c) to row-major flat (single wave: no barrier)
#pragma unroll
    for (int r = 0; r < 4; ++r) Zf[(4 * m + r) * 16 + c] = Acc[r];

    // out[b,o] = sum_k Zf[k]*W[o,k] + bias[o]; each lane covers k = lane+64j
    for (int o = 0; o < 10; ++o) {
        const float* wo = W + o * 256;
        float v = Zf[lane] * wo[lane];
        v = fmaf(Zf[lane + 64],  wo[lane + 64],  v);
        v = fmaf(Zf[lane + 128], wo[lane + 128], v);
        v = fmaf(Zf[lane + 192], wo[lane + 192], v);
#pragma unroll
        for (int off = 32; off >= 1; off >>= 1) v += __shfl_down(v, off, 64);
        if (lane == 0) out[b * 10 + o] = v + bias[o];
    }
}

extern "C" void kernel_launch(void* const* d_in, const int* in_sizes, int n_in,
                              void* d_out, int out_size, void* d_ws, size_t ws_size,
                              hipStream_t stream)
{
    const float* X    = (const float*)d_in[0];
    const float* A    = (const float*)d_in[1];
    const float* W    = (const float*)d_in[2];
    const float* bias = (const float*)d_in[3];
    float* out = (float*)d_out;
    float* G   = (float*)d_ws;   // 64*128*256 floats = 8 MB scratch

    devnet_expm_chunk<<<BSZ * NCH / 4, 256, 0, stream>>>(X, A, G);
    devnet_reduce1<<<BSZ * 4, 64, 0, stream>>>(G);
    devnet_reduce2<<<BSZ, 64, 0, stream>>>(G, W, bias, out);
}